// Round 6
// baseline (502.757 us; speedup 1.0000x reference)
//
#include <hip/hip_runtime.h>
#include <hip/hip_bf16.h>

#define Bb 4
#define Ss 2048
#define Dd 1024
#define Hh 16
#define DKk 64

typedef float f32x4 __attribute__((ext_vector_type(4)));
typedef short bf16x8 __attribute__((ext_vector_type(8)));
typedef unsigned short u16x4 __attribute__((ext_vector_type(4)));

#define MFMA16(a, b, c) __builtin_amdgcn_mfma_f32_16x16x32_bf16((a), (b), (c), 0, 0, 0)

__device__ __forceinline__ unsigned short f2bf(float f) {
  union { float f; unsigned u; } v;
  v.f = f;
  unsigned r = v.u + 0x7FFFu + ((v.u >> 16) & 1u);
  return (unsigned short)(r >> 16);
}

__device__ __forceinline__ float bf2f(unsigned short h) {
  union { unsigned u; float f; } v;
  v.u = ((unsigned)h) << 16;
  return v.f;
}

__device__ __forceinline__ float fast_exp2(float x) {
  float r;
  asm("v_exp_f32 %0, %1" : "=v"(r) : "v"(x));
  return r;
}

// pack 2 fp32 -> 2 bf16 (RNE) in one instruction
__device__ __forceinline__ unsigned cvt_pk_bf16(float lo, float hi) {
  unsigned r;
  asm("v_cvt_pk_bf16_f32 %0, %1, %2" : "=v"(r) : "v"(lo), "v"(hi));
  return r;
}

__device__ __forceinline__ bf16x8 cvt8(float4 f0, float4 f1) {
  bf16x8 r;
  r[0] = (short)f2bf(f0.x); r[1] = (short)f2bf(f0.y);
  r[2] = (short)f2bf(f0.z); r[3] = (short)f2bf(f0.w);
  r[4] = (short)f2bf(f1.x); r[5] = (short)f2bf(f1.y);
  r[6] = (short)f2bf(f1.z); r[7] = (short)f2bf(f1.w);
  return r;
}

// ---- cast fp32 -> bf16 for x, Wq, Wk, Wv, Wo (one launch) ----
__global__ __launch_bounds__(256) void cast_all(
    const float* __restrict__ x,  const float* __restrict__ Wq,
    const float* __restrict__ Wk, const float* __restrict__ Wv,
    const float* __restrict__ Wo,
    unsigned short* __restrict__ xb,  unsigned short* __restrict__ wqb,
    unsigned short* __restrict__ wkb, unsigned short* __restrict__ wvb,
    unsigned short* __restrict__ wob)
{
  int bid = blockIdx.x;
  const float* s; unsigned short* d; size_t base8;
  if (bid < 4096) { s = x; d = xb; base8 = (size_t)bid * 256; }
  else {
    int t = bid - 4096; int w = t >> 9; int off = t & 511;
    s = (w == 0) ? Wq : (w == 1) ? Wk : (w == 2) ? Wv : Wo;
    d = (w == 0) ? wqb : (w == 1) ? wkb : (w == 2) ? wvb : wob;
    base8 = (size_t)off * 256;
  }
  size_t i8 = base8 + threadIdx.x;
  const float4* sp = (const float4*)s + 2 * i8;
  float4 a = sp[0], b = sp[1];
  *(bf16x8*)(d + i8 * 8) = cvt8(a, b);
}

// ---- m97-style bf16 GEMM: C = A @ W.T (+bias), fused Q/K/V ----
// Q pre-scaled by 0.125*log2(e) (folds softmax scale AND exp->exp2 base change);
// V written TRANSPOSED [B,H,DK,S].
__global__ __launch_bounds__(256) void qkv_kernel(
    const unsigned short* __restrict__ xb,
    const unsigned short* __restrict__ wqb, const float* __restrict__ bq,
    const unsigned short* __restrict__ wkb, const float* __restrict__ bk_,
    const unsigned short* __restrict__ wvb, const float* __restrict__ bv_,
    unsigned short* __restrict__ qo, unsigned short* __restrict__ ko,
    unsigned short* __restrict__ vto)
{
  __shared__ __align__(16) unsigned short Al[128 * 64];
  __shared__ __align__(16) unsigned short Bl[128 * 64];
  const int tid = threadIdx.x, lane = tid & 63, wid = tid >> 6;
  const int m0 = blockIdx.x * 128;
  const int sel = blockIdx.y >> 3;
  const int n0 = (blockIdx.y & 7) * 128;
  const unsigned short* W; const float* bias;
  if (sel == 0)      { W = wqb; bias = bq;  }
  else if (sel == 1) { W = wkb; bias = bk_; }
  else               { W = wvb; bias = bv_; }
  const float prescale = (sel == 0) ? 0.180336880111f : 1.0f;  // 0.125*log2(e)

  const int wm = (wid >> 1) * 64, wn = (wid & 1) * 64;
  const int lr = lane & 15, lk8 = (lane >> 4) * 8;

  f32x4 acc[4][4] = {};
  const unsigned short* Abase = xb + (size_t)m0 * Dd;
  const unsigned short* Bbase = W + (size_t)n0 * Dd;

  for (int k0 = 0; k0 < Dd; k0 += 64) {
#pragma unroll
    for (int i = 0; i < 4; ++i) {
      int qq = (wid * 4 + i) * 64 + lane;
      int row = qq >> 3, c8 = qq & 7;
      const unsigned short* ga = Abase + (size_t)row * Dd + k0 + c8 * 8;
      const unsigned short* gb = Bbase + (size_t)row * Dd + k0 + c8 * 8;
      __builtin_amdgcn_global_load_lds(
          (const __attribute__((address_space(1))) unsigned int*)ga,
          (__attribute__((address_space(3))) unsigned int*)(Al + (wid * 4 + i) * 512),
          16, 0, 0);
      __builtin_amdgcn_global_load_lds(
          (const __attribute__((address_space(1))) unsigned int*)gb,
          (__attribute__((address_space(3))) unsigned int*)(Bl + (wid * 4 + i) * 512),
          16, 0, 0);
    }
    __syncthreads();
#pragma unroll
    for (int ks = 0; ks < 2; ++ks) {
      bf16x8 av[4], bv[4];
#pragma unroll
      for (int i = 0; i < 4; ++i)
        av[i] = *(const bf16x8*)&Al[(wm + i * 16 + lr) * 64 + ks * 32 + lk8];
#pragma unroll
      for (int j = 0; j < 4; ++j)
        bv[j] = *(const bf16x8*)&Bl[(wn + j * 16 + lr) * 64 + ks * 32 + lk8];
#pragma unroll
      for (int i = 0; i < 4; ++i)
#pragma unroll
        for (int j = 0; j < 4; ++j)
          acc[i][j] = MFMA16(av[i], bv[j], acc[i][j]);
    }
    __syncthreads();
  }

  const int rg = (lane >> 4) * 4;
  if (sel < 2) {
    unsigned short* out = (sel == 0) ? qo : ko;
#pragma unroll
    for (int i = 0; i < 4; ++i)
#pragma unroll
      for (int j = 0; j < 4; ++j) {
        int n = n0 + wn + j * 16 + lr;
        float bvv = bias[n];
        int hh = n >> 6, dk = n & 63;
#pragma unroll
        for (int r = 0; r < 4; ++r) {
          int m = m0 + wm + i * 16 + rg + r;
          int bb = m >> 11, ss = m & (Ss - 1);
          float v = (acc[i][j][r] + bvv) * prescale;
          out[((size_t)(bb * Hh + hh) * Ss + ss) * DKk + dk] = f2bf(v);
        }
      }
  } else {
    // V^T: [B,H,DK,S], pack 4 consecutive s per store
#pragma unroll
    for (int i = 0; i < 4; ++i) {
      int m_base = m0 + wm + i * 16 + rg;
      int bb = m_base >> 11, ss0 = m_base & (Ss - 1);
#pragma unroll
      for (int j = 0; j < 4; ++j) {
        int n = n0 + wn + j * 16 + lr;
        float bvv = bias[n];
        int hh = n >> 6, dk = n & 63;
        u16x4 pk;
#pragma unroll
        for (int r = 0; r < 4; ++r) pk[r] = f2bf(acc[i][j][r] + bvv);
        *(u16x4*)&vto[((size_t)(bb * Hh + hh) * DKk + dk) * Ss + ss0] = pk;
      }
    }
  }
}

// ---- fused attention: K register-prefetched (dbuf), V^T from global,
// exp2-direct scores, cvt_pk bf16 pack, coalesced NT attn stores ----
__global__ __launch_bounds__(256) void attn_kernel(
    const unsigned short* __restrict__ Qw, const unsigned short* __restrict__ Kw,
    const unsigned short* __restrict__ Vt, float* __restrict__ attn,
    unsigned short* __restrict__ OH)
{
  __shared__ unsigned short Pl[4][32][72];
  const int tid = threadIdx.x, lane = tid & 63, wid = tid >> 6;
  // XCD swizzle: head bh's 16 q-blocks land on XCD (bh&7)
  const int L = blockIdx.x;                 // 0..1023
  const int bh = (L & 7) + 8 * (L >> 7);
  const int qb = (L >> 3) & 15;
  const int q0 = qb * 128 + wid * 32;
  const unsigned short* Qh = Qw + (size_t)bh * Ss * DKk;
  const unsigned short* Kh = Kw + (size_t)bh * Ss * DKk;
  const unsigned short* Vh = Vt + (size_t)bh * DKk * Ss;   // [64 d][2048 s]
  const int lr = lane & 15;
  const int lk8 = (lane >> 4) * 8;
  const int rg = (lane >> 4) * 4;

  bf16x8 aq[2][2];
#pragma unroll
  for (int mi = 0; mi < 2; ++mi)
#pragma unroll
    for (int ks = 0; ks < 2; ++ks)
      aq[mi][ks] = *(const bf16x8*)&Qh[(size_t)(q0 + mi * 16 + lr) * DKk + ks * 32 + lk8];

#define LOADK(dst, kbase)                                                       \
  {                                                                             \
    _Pragma("unroll")                                                           \
    for (int nj = 0; nj < 4; ++nj) {                                            \
      _Pragma("unroll")                                                         \
      for (int ks = 0; ks < 2; ++ks)                                            \
        dst[nj][ks] = *(const bf16x8*)&Kh[(size_t)((kbase) + nj * 16 + lr) * DKk \
                                          + ks * 32 + lk8];                     \
    }                                                                           \
  }

  // ---- pass 1: l[q] = sum_k exp2(s) ----
  float lsum[2] = {0.f, 0.f};
  {
    bf16x8 kA[4][2], kB[4][2];
    LOADK(kA, 0);
    auto body1 = [&](bf16x8 (&bkt)[4][2], int kb) {
#pragma unroll
      for (int mi = 0; mi < 2; ++mi) {
        float acc = 0.f;
#pragma unroll
        for (int nj = 0; nj < 4; ++nj) {
          f32x4 c = {};
          c = MFMA16(bkt[nj][0], aq[mi][0], c);
          c = MFMA16(bkt[nj][1], aq[mi][1], c);
          acc += fast_exp2(c[0]) + fast_exp2(c[1]) +
                 fast_exp2(c[2]) + fast_exp2(c[3]);
        }
        lsum[mi] += acc;
      }
    };
    for (int kb = 0; kb < Ss; kb += 128) {
      LOADK(kB, kb + 64);
      body1(kA, kb);
      if (kb + 128 < Ss) LOADK(kA, kb + 128);
      body1(kB, kb + 64);
    }
  }
  float linv[2];
#pragma unroll
  for (int mi = 0; mi < 2; ++mi) {
    float l = lsum[mi];
    l += __shfl_xor(l, 16, 64);
    l += __shfl_xor(l, 32, 64);
    linv[mi] = 1.0f / l;
  }

  // ---- pass 2: recompute S^T, P->LDS(bf16), coalesced attn store, PV ----
  f32x4 o[2][4] = {};
  float* attn_bh = attn + (size_t)bh * Ss * Ss;
  {
    bf16x8 kA[4][2], kB[4][2];
    LOADK(kA, 0);
    const int c4 = (lane & 15) * 4;
    const int rsub = lane >> 4;
    auto body2 = [&](bf16x8 (&bkt)[4][2], int kb) {
      // V tile for this kb: issued here, consumed at PV (latency hidden)
      bf16x8 bvv[4][2];
#pragma unroll
      for (int nj = 0; nj < 4; ++nj)
#pragma unroll
        for (int ks = 0; ks < 2; ++ks)
          bvv[nj][ks] = *(const bf16x8*)&Vh[(size_t)(nj * 16 + lr) * Ss + kb + ks * 32 + lk8];

#pragma unroll
      for (int mi = 0; mi < 2; ++mi) {
        const float li = linv[mi];
#pragma unroll
        for (int nj = 0; nj < 4; ++nj) {
          f32x4 c = {};
          c = MFMA16(bkt[nj][0], aq[mi][0], c);   // S^T: col=q, row=key
          c = MFMA16(bkt[nj][1], aq[mi][1], c);
          float p0 = fast_exp2(c[0]) * li;
          float p1 = fast_exp2(c[1]) * li;
          float p2 = fast_exp2(c[2]) * li;
          float p3 = fast_exp2(c[3]) * li;
          uint2 w = {cvt_pk_bf16(p0, p1), cvt_pk_bf16(p2, p3)};
          *(uint2*)&Pl[wid][mi * 16 + lr][nj * 16 + rg] = w;
        }
      }
      // coalesced attn store: each instruction writes 4x256B contiguous rows
#pragma unroll
      for (int i = 0; i < 8; ++i) {
        int row = i * 4 + rsub;
        u16x4 pb4 = *(const u16x4*)&Pl[wid][row][c4];
        f32x4 pf;
        pf[0] = bf2f(pb4[0]); pf[1] = bf2f(pb4[1]);
        pf[2] = bf2f(pb4[2]); pf[3] = bf2f(pb4[3]);
        __builtin_nontemporal_store(pf,
            (f32x4*)(attn_bh + (size_t)(q0 + row) * Ss + kb + c4));
      }
      // PV: O += P @ V
#pragma unroll
      for (int ks = 0; ks < 2; ++ks) {
        const int kk = ks * 32 + lk8;
        bf16x8 ap[2];
#pragma unroll
        for (int mi = 0; mi < 2; ++mi)
          ap[mi] = *(const bf16x8*)&Pl[wid][mi * 16 + lr][kk];
#pragma unroll
        for (int mi = 0; mi < 2; ++mi)
#pragma unroll
          for (int nj = 0; nj < 4; ++nj)
            o[mi][nj] = MFMA16(ap[mi], bvv[nj][ks], o[mi][nj]);
      }
    };
    for (int kb = 0; kb < Ss; kb += 128) {
      LOADK(kB, kb + 64);
      body2(kA, kb);
      if (kb + 128 < Ss) LOADK(kA, kb + 128);
      body2(kB, kb + 64);
    }
  }
#undef LOADK

  // write O bf16 to [B,S,H,DK]
  const int b = bh >> 4, h = bh & 15;
#pragma unroll
  for (int mi = 0; mi < 2; ++mi)
#pragma unroll
    for (int nj = 0; nj < 4; ++nj)
#pragma unroll
      for (int r = 0; r < 4; ++r) {
        int q = q0 + mi * 16 + rg + r;
        int d = nj * 16 + lr;
        OH[(((size_t)b * Ss + q) * Hh + h) * DKk + d] = f2bf(o[mi][nj][r]);
      }
}

// ---- out = OH(bf16) @ Wo.T + bo, fp32 out, m97 structure ----
__global__ __launch_bounds__(256) void oproj_kernel(
    const unsigned short* __restrict__ A, const unsigned short* __restrict__ W,
    const float* __restrict__ bias, float* __restrict__ out)
{
  __shared__ __align__(16) unsigned short Al[128 * 64];
  __shared__ __align__(16) unsigned short Bl[128 * 64];
  const int tid = threadIdx.x, lane = tid & 63, wid = tid >> 6;
  const int m0 = blockIdx.x * 128;
  const int n0 = blockIdx.y * 128;
  const int wm = (wid >> 1) * 64, wn = (wid & 1) * 64;
  const int lr = lane & 15, lk8 = (lane >> 4) * 8;

  f32x4 acc[4][4] = {};
  const unsigned short* Abase = A + (size_t)m0 * Dd;
  const unsigned short* Bbase = W + (size_t)n0 * Dd;

  for (int k0 = 0; k0 < Dd; k0 += 64) {
#pragma unroll
    for (int i = 0; i < 4; ++i) {
      int qq = (wid * 4 + i) * 64 + lane;
      int row = qq >> 3, c8 = qq & 7;
      const unsigned short* ga = Abase + (size_t)row * Dd + k0 + c8 * 8;
      const unsigned short* gb = Bbase + (size_t)row * Dd + k0 + c8 * 8;
      __builtin_amdgcn_global_load_lds(
          (const __attribute__((address_space(1))) unsigned int*)ga,
          (__attribute__((address_space(3))) unsigned int*)(Al + (wid * 4 + i) * 512),
          16, 0, 0);
      __builtin_amdgcn_global_load_lds(
          (const __attribute__((address_space(1))) unsigned int*)gb,
          (__attribute__((address_space(3))) unsigned int*)(Bl + (wid * 4 + i) * 512),
          16, 0, 0);
    }
    __syncthreads();
#pragma unroll
    for (int ks = 0; ks < 2; ++ks) {
      bf16x8 av[4], bv[4];
#pragma unroll
      for (int i = 0; i < 4; ++i)
        av[i] = *(const bf16x8*)&Al[(wm + i * 16 + lr) * 64 + ks * 32 + lk8];
#pragma unroll
      for (int j = 0; j < 4; ++j)
        bv[j] = *(const bf16x8*)&Bl[(wn + j * 16 + lr) * 64 + ks * 32 + lk8];
#pragma unroll
      for (int i = 0; i < 4; ++i)
#pragma unroll
        for (int j = 0; j < 4; ++j)
          acc[i][j] = MFMA16(av[i], bv[j], acc[i][j]);
    }
    __syncthreads();
  }

  const int rg = (lane >> 4) * 4;
#pragma unroll
  for (int i = 0; i < 4; ++i)
#pragma unroll
    for (int j = 0; j < 4; ++j) {
      int n = n0 + wn + j * 16 + lr;
      float bvv = bias[n];
#pragma unroll
      for (int r = 0; r < 4; ++r) {
        int m = m0 + wm + i * 16 + rg + r;
        out[(size_t)m * Dd + n] = acc[i][j][r] + bvv;
      }
    }
}

extern "C" void kernel_launch(void* const* d_in, const int* in_sizes, int n_in,
                              void* d_out, int out_size, void* d_ws, size_t ws_size,
                              hipStream_t stream) {
  const float* x  = (const float*)d_in[0];
  const float* Wq = (const float*)d_in[1];
  const float* bq = (const float*)d_in[2];
  const float* Wk = (const float*)d_in[3];
  const float* bk = (const float*)d_in[4];
  const float* Wv = (const float*)d_in[5];
  const float* bv = (const float*)d_in[6];
  const float* Wo = (const float*)d_in[7];
  const float* bo = (const float*)d_in[8];

  float* out  = (float*)d_out;
  float* attn = out + (size_t)Bb * Ss * Dd;

  const size_t headElems = (size_t)Bb * Hh * Ss * DKk;  // 8,388,608
  const size_t wElems = (size_t)Dd * Dd;                // 1,048,576
  unsigned short* qws  = (unsigned short*)d_ws;
  unsigned short* kws  = qws + headElems;
  unsigned short* vtws = kws + headElems;
  unsigned short* ohw  = vtws + headElems;
  unsigned short* xb   = ohw + headElems;
  unsigned short* wqb  = xb + headElems;
  unsigned short* wkb  = wqb + wElems;
  unsigned short* wvb  = wkb + wElems;
  unsigned short* wob  = wvb + wElems;

  dim3 blk(256);
  cast_all<<<dim3(6144), blk, 0, stream>>>(x, Wq, Wk, Wv, Wo, xb, wqb, wkb, wvb, wob);
  qkv_kernel<<<dim3(64, 24), blk, 0, stream>>>(xb, wqb, bq, wkb, bk, wvb, bv,
                                               qws, kws, vtws);
  attn_kernel<<<dim3(1024), blk, 0, stream>>>(qws, kws, vtws, attn, ohw);
  oproj_kernel<<<dim3(64, 8), blk, 0, stream>>>(ohw, wob, bo, out);
}